// Round 1
// baseline (268.165 us; speedup 1.0000x reference)
//
#include <hip/hip_runtime.h>
#include <cstdint>

#define DIMC 1024
#define NSEQ 2048
#define BATCH 2
#define HEADS 16
#define HD 64
#define MROWS (BATCH * NSEQ) /* 4096 */

typedef unsigned short u16;
typedef unsigned int u32;
typedef __attribute__((ext_vector_type(8))) short bf16x8;
typedef __attribute__((ext_vector_type(4))) short bf16x4;
typedef __attribute__((ext_vector_type(4))) float f32x4;

#if __has_builtin(__builtin_amdgcn_exp2f)
#define EXP2(x) __builtin_amdgcn_exp2f(x)
#else
#define EXP2(x) exp2f(x)
#endif

__device__ __forceinline__ u16 f2bf(float f) {
  union { float f; u32 u; } v; v.f = f;
  u32 u = v.u;
  return (u16)((u + 0x7fffu + ((u >> 16) & 1u)) >> 16);
}
__device__ __forceinline__ u32 pack_rne(float a, float b) {
  return (u32)f2bf(a) | ((u32)f2bf(b) << 16);
}
__device__ __forceinline__ u32 pack_trunc(float a, float b) {
  union { float f; u32 u; } x, y; x.f = a; y.f = b;
  return (x.u >> 16) | (y.u & 0xffff0000u);
}
// async global->LDS, 16B per lane. LDS dest must be wave-uniform base + lane*16.
__device__ __forceinline__ void gload_lds16(const void* g, void* l) {
  __builtin_amdgcn_global_load_lds((const __attribute__((address_space(1))) void*)g,
                                   (__attribute__((address_space(3))) void*)l, 16, 0, 0);
}

// ---------------- prep: LayerNorm+cast (blocks 0..12287) & W transpose+cast ----
__global__ __launch_bounds__(256)
void prep(const float* __restrict__ q, const float* __restrict__ k,
          const float* __restrict__ v,
          const float* __restrict__ gq, const float* __restrict__ bq,
          const float* __restrict__ gk, const float* __restrict__ bk,
          const float* __restrict__ gv, const float* __restrict__ bv,
          const float* __restrict__ w0, const float* __restrict__ w1,
          const float* __restrict__ w2, const float* __restrict__ w3,
          u16* __restrict__ xn, u16* __restrict__ wtout) {
  __shared__ float rs[4], rs2[4];
  __shared__ float tile[32][33];
  int tid = threadIdx.x;
  if (blockIdx.x < 3 * MROWS) {
    int rowid = blockIdx.x;
    int tensor = rowid >> 12;
    int r = rowid & 4095;
    const float *src, *g, *b;
    if (tensor == 0)      { src = q; g = gq; b = bq; }
    else if (tensor == 1) { src = k; g = gk; b = bk; }
    else                  { src = v; g = gv; b = bv; }
    src += (size_t)r * DIMC;
    u16* dst = xn + (size_t)tensor * MROWS * DIMC + (size_t)r * DIMC;
    float4 x = ((const float4*)src)[tid];
    float s  = x.x + x.y + x.z + x.w;
    float s2 = x.x*x.x + x.y*x.y + x.z*x.z + x.w*x.w;
    #pragma unroll
    for (int m = 1; m < 64; m <<= 1) { s += __shfl_xor(s, m); s2 += __shfl_xor(s2, m); }
    int wave = tid >> 6, lane = tid & 63;
    if (lane == 0) { rs[wave] = s; rs2[wave] = s2; }
    __syncthreads();
    s  = rs[0] + rs[1] + rs[2] + rs[3];
    s2 = rs2[0] + rs2[1] + rs2[2] + rs2[3];
    float mu  = s * (1.0f / DIMC);
    float var = s2 * (1.0f / DIMC) - mu * mu;
    float inv = rsqrtf(var + 1e-5f);
    float4 gg = ((const float4*)g)[tid];
    float4 bb = ((const float4*)b)[tid];
    uint2 o;
    o.x = pack_rne((x.x - mu) * inv * gg.x + bb.x, (x.y - mu) * inv * gg.y + bb.y);
    o.y = pack_rne((x.z - mu) * inv * gg.z + bb.z, (x.w - mu) * inv * gg.w + bb.w);
    ((uint2*)dst)[tid] = o;
  } else {
    int blk = blockIdx.x - 3 * MROWS;
    int widx = blk >> 10, t = blk & 1023;
    int ti = t >> 5, tj = t & 31;
    const float* W = (widx == 0) ? w0 : (widx == 1) ? w1 : (widx == 2) ? w2 : w3;
    u16* O = wtout + (size_t)widx * DIMC * DIMC;
    int tx = tid & 31, ty = tid >> 5;
    #pragma unroll
    for (int rr = 0; rr < 32; rr += 8)
      tile[ty + rr][tx] = W[(size_t)(ti * 32 + ty + rr) * DIMC + tj * 32 + tx];
    __syncthreads();
    #pragma unroll
    for (int rr = 0; rr < 32; rr += 8)
      O[(size_t)(tj * 32 + ty + rr) * DIMC + ti * 32 + tx] = f2bf(tile[tx][ty + rr]);
  }
}

// ---------------- fused QKV projection GEMM (grid.z selects Q/K/V) ----------------
// z==2 epilogue also produces V^T [bh][d][n] via LDS transpose (padded stride 136).
__global__ __launch_bounds__(256)
void qkv_gemm(const u16* __restrict__ xn, const u16* __restrict__ wt,
              const float* __restrict__ bq, const float* __restrict__ bk,
              const float* __restrict__ bv,
              float* __restrict__ out, u16* __restrict__ qh,
              u16* __restrict__ khb, u16* __restrict__ vtb) {
  __shared__ u16 smem[128 * 136];           // 34.8 KB; front 16 KB doubles as As/Bs
  u16* As = smem;                            // 128*32
  u16* Bs = smem + 4096;                     // 128*32
  u16* Ls = smem;                            // transpose tile [c][m] stride 136
  const int z = blockIdx.z;
  const u16* A  = xn + (size_t)z * MROWS * DIMC;
  const u16* Bt = wt + (size_t)z * DIMC * DIMC;
  const float* bias = (z == 0) ? bq : (z == 1) ? bk : bv;
  const int bm = blockIdx.x, bn = blockIdx.y;
  const int tid = threadIdx.x;
  const int wave = tid >> 6, lane = tid & 63;
  const int wm = (wave & 1) * 64, wn = (wave >> 1) * 64;
  const int row = lane & 15, quad = lane >> 4;
  const float QSCL = 0.18033688011112042f;  // 0.125 * log2(e)
  f32x4 acc[4][4] = {};
  for (int k0 = 0; k0 < DIMC; k0 += 32) {
    #pragma unroll
    for (int c = 0; c < 2; ++c) {
      int e = c * 2048 + tid * 8;
      int rr = e >> 5, col = e & 31;
      gload_lds16(&A[(size_t)(bm * 128 + rr) * DIMC + k0 + col], &As[e]);
      gload_lds16(&Bt[(size_t)(bn * 128 + rr) * DIMC + k0 + col], &Bs[e]);
    }
    __syncthreads();
    bf16x8 a[4], b[4];
    #pragma unroll
    for (int i = 0; i < 4; ++i)
      a[i] = *(const bf16x8*)(&As[(wm + i * 16 + row) * 32 + quad * 8]);
    #pragma unroll
    for (int j = 0; j < 4; ++j)
      b[j] = *(const bf16x8*)(&Bs[(wn + j * 16 + row) * 32 + quad * 8]);
    #pragma unroll
    for (int i = 0; i < 4; ++i)
      #pragma unroll
      for (int j = 0; j < 4; ++j)
        acc[i][j] = __builtin_amdgcn_mfma_f32_16x16x32_bf16(a[i], b[j], acc[i][j], 0, 0, 0);
    __syncthreads();
  }
  #pragma unroll
  for (int i = 0; i < 4; ++i) {
    #pragma unroll
    for (int j = 0; j < 4; ++j) {
      float val[4];
      #pragma unroll
      for (int r = 0; r < 4; ++r) {
        int m = bm * 128 + wm + i * 16 + quad * 4 + r;
        int c = bn * 128 + wn + j * 16 + row;
        val[r] = acc[i][j][r] + bias[c];
        int b_ = m >> 11, n = m & 2047, h = c >> 6, d = c & 63;
        int bh = b_ * HEADS + h;
        size_t hidx = ((size_t)bh * NSEQ + n) * HD + d;
        if (z == 0) {
          qh[hidx] = f2bf(val[r] * QSCL);   // pre-scaled for attention exp2
        } else {
          out[(size_t)z * MROWS * DIMC + hidx] = val[r];
          if (z == 1) khb[hidx] = f2bf(val[r]);
        }
      }
      if (z == 2) {
        int ct = wn + j * 16 + row;
        int mt = wm + i * 16 + quad * 4;
        u32* L = (u32*)(&Ls[ct * 136 + mt]);
        L[0] = pack_rne(val[0], val[1]);
        L[1] = pack_rne(val[2], val[3]);
      }
    }
  }
  if (z == 2) {
    __syncthreads();
    int b_ = (bm * 128) >> 11;
    int nbase = (bm * 128) & 2047;
    #pragma unroll
    for (int it = 0; it < 8; ++it) {
      int idx = it * 256 + tid;
      int ct = idx >> 4, ch = idx & 15;     // ct = c within tile, ch = 8-m chunk
      uint4 y = *(const uint4*)(&Ls[ct * 136 + ch * 8]);
      int c = bn * 128 + ct;
      int h = c >> 6, d = c & 63;
      size_t o = ((size_t)(b_ * HEADS + h) * HD + d) * NSEQ + nbase + ch * 8;
      *(uint4*)(&vtb[o]) = y;
    }
  }
}

// ---------------- output projection GEMM (64x128 tile, fp32 row-major out) ------
__global__ __launch_bounds__(256)
void out_gemm(const u16* __restrict__ A, const u16* __restrict__ Bt,
              const float* __restrict__ bias, float* __restrict__ outf) {
  __shared__ u16 As[64 * 32];
  __shared__ u16 Bs[128 * 32];
  const int bm = blockIdx.x, bn = blockIdx.y;
  const int tid = threadIdx.x;
  const int wave = tid >> 6, lane = tid & 63;
  const int wm = (wave & 1) * 32, wn = (wave >> 1) * 64;
  const int row = lane & 15, quad = lane >> 4;
  f32x4 acc[2][4] = {};
  for (int k0 = 0; k0 < DIMC; k0 += 32) {
    {
      int e = tid * 8;
      int rr = e >> 5, col = e & 31;
      gload_lds16(&A[(size_t)(bm * 64 + rr) * DIMC + k0 + col], &As[e]);
    }
    #pragma unroll
    for (int c = 0; c < 2; ++c) {
      int e = c * 2048 + tid * 8;
      int rr = e >> 5, col = e & 31;
      gload_lds16(&Bt[(size_t)(bn * 128 + rr) * DIMC + k0 + col], &Bs[e]);
    }
    __syncthreads();
    bf16x8 a[2], b[4];
    #pragma unroll
    for (int i = 0; i < 2; ++i)
      a[i] = *(const bf16x8*)(&As[(wm + i * 16 + row) * 32 + quad * 8]);
    #pragma unroll
    for (int j = 0; j < 4; ++j)
      b[j] = *(const bf16x8*)(&Bs[(wn + j * 16 + row) * 32 + quad * 8]);
    #pragma unroll
    for (int i = 0; i < 2; ++i)
      #pragma unroll
      for (int j = 0; j < 4; ++j)
        acc[i][j] = __builtin_amdgcn_mfma_f32_16x16x32_bf16(a[i], b[j], acc[i][j], 0, 0, 0);
    __syncthreads();
  }
  #pragma unroll
  for (int i = 0; i < 2; ++i)
    #pragma unroll
    for (int j = 0; j < 4; ++j)
      #pragma unroll
      for (int r = 0; r < 4; ++r) {
        int m = bm * 64 + wm + i * 16 + quad * 4 + r;
        int c = bn * 128 + wn + j * 16 + row;
        outf[(size_t)m * DIMC + c] = acc[i][j][r] + bias[c];
      }
}

// ---------------- fused flash attention (64-q blocks, streaming 32-key P) -------
// grid (32 qtiles of 64, 32 bh), 4 waves; wave owns 16 q rows.
// qh pre-scaled by SCALE*log2(e). Per 32-key chunk: S^T -> exp -> P kept fully
// IN REGISTER via k-slot permutation (MFMA k-reduction is order-invariant, so
// we permute the k dimension of BOTH PV operands: slot quad*8+e -> key
// kc*32 + quad*4+e (e<4) / kc*32+16+quad*4+(e-4) (e>=4); with that ordering
// the B-fragment is exactly the lane's own 8 exp results — no LDS round-trip,
// no cross-lane exchange). V^T A-fragments read as 2x ds_read_b64 from the
// chunk-swizzled Vs (uniform over banks). LDS 32 KB.
__global__ __launch_bounds__(256)
void attn_fused(const u16* __restrict__ qh, const u16* __restrict__ kh,
                const u16* __restrict__ vt, u16* __restrict__ ao) {
  __shared__ u16 Ks[128 * 64];       // [key][d] chunk-swizzled
  __shared__ u16 Vs[64 * 128];       // [d][key] chunk-swizzled
  const int qtile = blockIdx.x;
  const int bh = blockIdx.y;
  const int b = bh >> 4, h = bh & 15;
  const int tid = threadIdx.x;
  const int wave = tid >> 6, lane = tid & 63;
  const int qi = lane & 15, quad = lane >> 4;
  const int sw = qi & 7;
  const size_t base = (size_t)bh * NSEQ * HD;
  bf16x8 qf[2];
  {
    int qrow = qtile * 64 + wave * 16 + qi;
    #pragma unroll
    for (int kc = 0; kc < 2; ++kc)
      qf[kc] = *(const bf16x8*)(&qh[base + (size_t)qrow * HD + kc * 32 + quad * 8]);
  }
  float li = 0.f;
  f32x4 oacc[4] = {};
  for (int kt = 0; kt < NSEQ / 128; ++kt) {
    __syncthreads();
    #pragma unroll
    for (int c = 0; c < 4; ++c) {
      int p = c * 256 + tid;
      int rk = p >> 3, ck = p & 7;
      gload_lds16(&kh[base + (size_t)(kt * 128 + rk) * HD + (ck ^ (rk & 7)) * 8], &Ks[p * 8]);
      int rv = p >> 4, cv = p & 15;
      gload_lds16(&vt[base + (size_t)rv * NSEQ + kt * 128 + (cv ^ (rv & 15)) * 8], &Vs[p * 8]);
    }
    __syncthreads();
    #pragma unroll
    for (int kc = 0; kc < 4; ++kc) {
      // K fragments: two 16-key S^T tiles of this 32-key chunk
      const u16* kr0 = &Ks[((kc * 2) * 16 + qi) * 64];
      const u16* kr1 = &Ks[((kc * 2 + 1) * 16 + qi) * 64];
      bf16x8 k0a = *(const bf16x8*)(&kr0[(quad ^ sw) * 8]);
      bf16x8 k0b = *(const bf16x8*)(&kr0[((4 + quad) ^ sw) * 8]);
      bf16x8 k1a = *(const bf16x8*)(&kr1[(quad ^ sw) * 8]);
      bf16x8 k1b = *(const bf16x8*)(&kr1[((4 + quad) ^ sw) * 8]);
      // V fragments in permuted k-slot order: two b64 reads per dt.
      // global key group [kc*32+quad*4, +4)  -> logical chunk kc*4+(quad>>1),  half quad&1
      // global key group [kc*32+16+quad*4,.) -> logical chunk kc*4+2+(quad>>1), half quad&1
      // physical chunk = logical ^ (row&15) = logical ^ qi
      bf16x8 vfr[4];
      #pragma unroll
      for (int dt = 0; dt < 4; ++dt) {
        const u16* vrow = &Vs[(dt * 16 + qi) * 128];
        int c0 = (kc * 4 + (quad >> 1)) ^ qi;
        int c1 = (kc * 4 + 2 + (quad >> 1)) ^ qi;
        bf16x4 vlo = *(const bf16x4*)(&vrow[c0 * 8 + (quad & 1) * 4]);
        bf16x4 vhi = *(const bf16x4*)(&vrow[c1 * 8 + (quad & 1) * 4]);
        vfr[dt] = __builtin_shufflevector(vlo, vhi, 0, 1, 2, 3, 4, 5, 6, 7);
      }
      f32x4 s0 = {}, s1 = {};
      __builtin_amdgcn_s_setprio(1);
      s0 = __builtin_amdgcn_mfma_f32_16x16x32_bf16(k0a, qf[0], s0, 0, 0, 0);
      s0 = __builtin_amdgcn_mfma_f32_16x16x32_bf16(k0b, qf[1], s0, 0, 0, 0);
      s1 = __builtin_amdgcn_mfma_f32_16x16x32_bf16(k1a, qf[0], s1, 0, 0, 0);
      s1 = __builtin_amdgcn_mfma_f32_16x16x32_bf16(k1b, qf[1], s1, 0, 0, 0);
      __builtin_amdgcn_s_setprio(0);
      float p0 = EXP2(s0[0]), p1 = EXP2(s0[1]), p2 = EXP2(s0[2]), p3 = EXP2(s0[3]);
      float p4 = EXP2(s1[0]), p5 = EXP2(s1[1]), p6 = EXP2(s1[2]), p7 = EXP2(s1[3]);
      float psum = ((p0 + p1) + (p2 + p3)) + ((p4 + p5) + (p6 + p7));
      psum += __shfl_xor(psum, 16);
      psum += __shfl_xor(psum, 32);
      li += psum;
      union { bf16x8 v; u32 u[4]; } pu;
      pu.u[0] = pack_trunc(p0, p1);
      pu.u[1] = pack_trunc(p2, p3);
      pu.u[2] = pack_trunc(p4, p5);
      pu.u[3] = pack_trunc(p6, p7);
      __builtin_amdgcn_s_setprio(1);
      #pragma unroll
      for (int dt = 0; dt < 4; ++dt)
        oacc[dt] = __builtin_amdgcn_mfma_f32_16x16x32_bf16(vfr[dt], pu.v, oacc[dt], 0, 0, 0);
      __builtin_amdgcn_s_setprio(0);
    }
  }
  {
    float inv = 1.0f / li;
    int token = b * NSEQ + qtile * 64 + wave * 16 + qi;
    #pragma unroll
    for (int dt = 0; dt < 4; ++dt) {
      int col = h * 64 + dt * 16 + quad * 4;
      *(u32*)(&ao[(size_t)token * DIMC + col])     = pack_rne(oacc[dt][0] * inv, oacc[dt][1] * inv);
      *(u32*)(&ao[(size_t)token * DIMC + col + 2]) = pack_rne(oacc[dt][2] * inv, oacc[dt][3] * inv);
    }
  }
}

extern "C" void kernel_launch(void* const* d_in, const int* in_sizes, int n_in,
                              void* d_out, int out_size, void* d_ws, size_t ws_size,
                              hipStream_t stream) {
  const float* q    = (const float*)d_in[0];
  const float* k    = (const float*)d_in[1];
  const float* v    = (const float*)d_in[2];
  const float* gq   = (const float*)d_in[3];
  const float* bqln = (const float*)d_in[4];
  const float* gk   = (const float*)d_in[5];
  const float* bkln = (const float*)d_in[6];
  const float* gv   = (const float*)d_in[7];
  const float* bvln = (const float*)d_in[8];
  const float* Wq   = (const float*)d_in[9];
  const float* bq   = (const float*)d_in[10];
  const float* Wk   = (const float*)d_in[11];
  const float* bk   = (const float*)d_in[12];
  const float* Wv   = (const float*)d_in[13];
  const float* bv   = (const float*)d_in[14];
  const float* Wp   = (const float*)d_in[15];
  const float* bp   = (const float*)d_in[16];
  float* out = (float*)d_out;

  char* ws = (char*)d_ws;
  u16* xn  = (u16*)(ws);                          // 3 x 4096x1024 bf16 (24MB)
  u16* wt  = (u16*)(ws + (size_t)25165824);       // 4 x 1024x1024 bf16 (8MB)
  u16* qh  = (u16*)(ws + (size_t)33554432);       // [bh][n][d] bf16 (pre-scaled)
  u16* khb = (u16*)(ws + (size_t)41943040);       // [bh][n][d] bf16
  u16* ao  = (u16*)(ws + (size_t)50331648);       // [token][1024] bf16
  // V^T lives in the output-0 region of d_out (16.78 MB, exactly fits);
  // out_gemm overwrites it afterwards.
  u16* vtb = (u16*)d_out;                         // [bh][d][n] bf16

  const size_t WEL = (size_t)DIMC * DIMC;

  prep<<<3 * MROWS + 4096, 256, 0, stream>>>(q, k, v, gq, bqln, gk, bkln, gv, bvln,
                                             Wq, Wk, Wv, Wp, xn, wt);
  qkv_gemm<<<dim3(MROWS / 128, DIMC / 128, 3), 256, 0, stream>>>(
      xn, wt, bq, bk, bv, out, qh, khb, vtb);
  attn_fused<<<dim3(NSEQ / 64, BATCH * HEADS), 256, 0, stream>>>(qh, khb, vtb, ao);
  out_gemm<<<dim3(MROWS / 64, DIMC / 128), 256, 0, stream>>>(ao, wt + 3 * WEL, bp, out);
}

// Round 2
// 256.291 us; speedup vs baseline: 1.0463x; 1.0463x over previous
//
#include <hip/hip_runtime.h>
#include <cstdint>

#define DIMC 1024
#define NSEQ 2048
#define BATCH 2
#define HEADS 16
#define HD 64
#define MROWS (BATCH * NSEQ) /* 4096 */

typedef unsigned short u16;
typedef unsigned int u32;
typedef __attribute__((ext_vector_type(8))) short bf16x8;
typedef __attribute__((ext_vector_type(4))) float f32x4;

#if __has_builtin(__builtin_amdgcn_exp2f)
#define EXP2(x) __builtin_amdgcn_exp2f(x)
#else
#define EXP2(x) exp2f(x)
#endif

__device__ __forceinline__ u16 f2bf(float f) {
  union { float f; u32 u; } v; v.f = f;
  u32 u = v.u;
  return (u16)((u + 0x7fffu + ((u >> 16) & 1u)) >> 16);
}
__device__ __forceinline__ u32 pack_rne(float a, float b) {
  return (u32)f2bf(a) | ((u32)f2bf(b) << 16);
}
__device__ __forceinline__ u32 pack_trunc(float a, float b) {
  union { float f; u32 u; } x, y; x.f = a; y.f = b;
  return (x.u >> 16) | (y.u & 0xffff0000u);
}
// async global->LDS, 16B per lane. LDS dest must be wave-uniform base + lane*16.
__device__ __forceinline__ void gload_lds16(const void* g, void* l) {
  __builtin_amdgcn_global_load_lds((const __attribute__((address_space(1))) void*)g,
                                   (__attribute__((address_space(3))) void*)l, 16, 0, 0);
}

// ---------------- prep: LayerNorm+cast (blocks 0..12287) & W transpose+cast ----
__global__ __launch_bounds__(256)
void prep(const float* __restrict__ q, const float* __restrict__ k,
          const float* __restrict__ v,
          const float* __restrict__ gq, const float* __restrict__ bq,
          const float* __restrict__ gk, const float* __restrict__ bk,
          const float* __restrict__ gv, const float* __restrict__ bv,
          const float* __restrict__ w0, const float* __restrict__ w1,
          const float* __restrict__ w2, const float* __restrict__ w3,
          u16* __restrict__ xn, u16* __restrict__ wtout) {
  __shared__ float rs[4], rs2[4];
  __shared__ float tile[32][33];
  int tid = threadIdx.x;
  if (blockIdx.x < 3 * MROWS) {
    int rowid = blockIdx.x;
    int tensor = rowid >> 12;
    int r = rowid & 4095;
    const float *src, *g, *b;
    if (tensor == 0)      { src = q; g = gq; b = bq; }
    else if (tensor == 1) { src = k; g = gk; b = bk; }
    else                  { src = v; g = gv; b = bv; }
    src += (size_t)r * DIMC;
    u16* dst = xn + (size_t)tensor * MROWS * DIMC + (size_t)r * DIMC;
    float4 x = ((const float4*)src)[tid];
    float s  = x.x + x.y + x.z + x.w;
    float s2 = x.x*x.x + x.y*x.y + x.z*x.z + x.w*x.w;
    #pragma unroll
    for (int m = 1; m < 64; m <<= 1) { s += __shfl_xor(s, m); s2 += __shfl_xor(s2, m); }
    int wave = tid >> 6, lane = tid & 63;
    if (lane == 0) { rs[wave] = s; rs2[wave] = s2; }
    __syncthreads();
    s  = rs[0] + rs[1] + rs[2] + rs[3];
    s2 = rs2[0] + rs2[1] + rs2[2] + rs2[3];
    float mu  = s * (1.0f / DIMC);
    float var = s2 * (1.0f / DIMC) - mu * mu;
    float inv = rsqrtf(var + 1e-5f);
    float4 gg = ((const float4*)g)[tid];
    float4 bb = ((const float4*)b)[tid];
    uint2 o;
    o.x = pack_rne((x.x - mu) * inv * gg.x + bb.x, (x.y - mu) * inv * gg.y + bb.y);
    o.y = pack_rne((x.z - mu) * inv * gg.z + bb.z, (x.w - mu) * inv * gg.w + bb.w);
    ((uint2*)dst)[tid] = o;
  } else {
    int blk = blockIdx.x - 3 * MROWS;
    int widx = blk >> 10, t = blk & 1023;
    int ti = t >> 5, tj = t & 31;
    const float* W = (widx == 0) ? w0 : (widx == 1) ? w1 : (widx == 2) ? w2 : w3;
    u16* O = wtout + (size_t)widx * DIMC * DIMC;
    int tx = tid & 31, ty = tid >> 5;
    #pragma unroll
    for (int rr = 0; rr < 32; rr += 8)
      tile[ty + rr][tx] = W[(size_t)(ti * 32 + ty + rr) * DIMC + tj * 32 + tx];
    __syncthreads();
    #pragma unroll
    for (int rr = 0; rr < 32; rr += 8)
      O[(size_t)(tj * 32 + ty + rr) * DIMC + ti * 32 + tx] = f2bf(tile[tx][ty + rr]);
  }
}

// ---------------- fused QKV projection GEMM (grid.z selects Q/K/V) ----------------
// z==2 epilogue also produces V^T [bh][d][n] via LDS transpose (padded stride 136).
__global__ __launch_bounds__(256)
void qkv_gemm(const u16* __restrict__ xn, const u16* __restrict__ wt,
              const float* __restrict__ bq, const float* __restrict__ bk,
              const float* __restrict__ bv,
              float* __restrict__ out, u16* __restrict__ qh,
              u16* __restrict__ khb, u16* __restrict__ vtb) {
  __shared__ u16 smem[128 * 136];           // 34.8 KB; front 16 KB doubles as As/Bs
  u16* As = smem;                            // 128*32
  u16* Bs = smem + 4096;                     // 128*32
  u16* Ls = smem;                            // transpose tile [c][m] stride 136
  const int z = blockIdx.z;
  const u16* A  = xn + (size_t)z * MROWS * DIMC;
  const u16* Bt = wt + (size_t)z * DIMC * DIMC;
  const float* bias = (z == 0) ? bq : (z == 1) ? bk : bv;
  const int bm = blockIdx.x, bn = blockIdx.y;
  const int tid = threadIdx.x;
  const int wave = tid >> 6, lane = tid & 63;
  const int wm = (wave & 1) * 64, wn = (wave >> 1) * 64;
  const int row = lane & 15, quad = lane >> 4;
  const float QSCL = 0.18033688011112042f;  // 0.125 * log2(e)
  f32x4 acc[4][4] = {};
  for (int k0 = 0; k0 < DIMC; k0 += 32) {
    #pragma unroll
    for (int c = 0; c < 2; ++c) {
      int e = c * 2048 + tid * 8;
      int rr = e >> 5, col = e & 31;
      gload_lds16(&A[(size_t)(bm * 128 + rr) * DIMC + k0 + col], &As[e]);
      gload_lds16(&Bt[(size_t)(bn * 128 + rr) * DIMC + k0 + col], &Bs[e]);
    }
    __syncthreads();
    bf16x8 a[4], b[4];
    #pragma unroll
    for (int i = 0; i < 4; ++i)
      a[i] = *(const bf16x8*)(&As[(wm + i * 16 + row) * 32 + quad * 8]);
    #pragma unroll
    for (int j = 0; j < 4; ++j)
      b[j] = *(const bf16x8*)(&Bs[(wn + j * 16 + row) * 32 + quad * 8]);
    #pragma unroll
    for (int i = 0; i < 4; ++i)
      #pragma unroll
      for (int j = 0; j < 4; ++j)
        acc[i][j] = __builtin_amdgcn_mfma_f32_16x16x32_bf16(a[i], b[j], acc[i][j], 0, 0, 0);
    __syncthreads();
  }
  #pragma unroll
  for (int i = 0; i < 4; ++i) {
    #pragma unroll
    for (int j = 0; j < 4; ++j) {
      float val[4];
      #pragma unroll
      for (int r = 0; r < 4; ++r) {
        int m = bm * 128 + wm + i * 16 + quad * 4 + r;
        int c = bn * 128 + wn + j * 16 + row;
        val[r] = acc[i][j][r] + bias[c];
        int b_ = m >> 11, n = m & 2047, h = c >> 6, d = c & 63;
        int bh = b_ * HEADS + h;
        size_t hidx = ((size_t)bh * NSEQ + n) * HD + d;
        if (z == 0) {
          qh[hidx] = f2bf(val[r] * QSCL);   // pre-scaled for attention exp2
        } else {
          out[(size_t)z * MROWS * DIMC + hidx] = val[r];
          if (z == 1) khb[hidx] = f2bf(val[r]);
        }
      }
      if (z == 2) {
        int ct = wn + j * 16 + row;
        int mt = wm + i * 16 + quad * 4;
        u32* L = (u32*)(&Ls[ct * 136 + mt]);
        L[0] = pack_rne(val[0], val[1]);
        L[1] = pack_rne(val[2], val[3]);
      }
    }
  }
  if (z == 2) {
    __syncthreads();
    int b_ = (bm * 128) >> 11;
    int nbase = (bm * 128) & 2047;
    #pragma unroll
    for (int it = 0; it < 8; ++it) {
      int idx = it * 256 + tid;
      int ct = idx >> 4, ch = idx & 15;     // ct = c within tile, ch = 8-m chunk
      uint4 y = *(const uint4*)(&Ls[ct * 136 + ch * 8]);
      int c = bn * 128 + ct;
      int h = c >> 6, d = c & 63;
      size_t o = ((size_t)(b_ * HEADS + h) * HD + d) * NSEQ + nbase + ch * 8;
      *(uint4*)(&vtb[o]) = y;
    }
  }
}

// ---------------- output projection GEMM (64x128 tile, fp32 row-major out) ------
__global__ __launch_bounds__(256)
void out_gemm(const u16* __restrict__ A, const u16* __restrict__ Bt,
              const float* __restrict__ bias, float* __restrict__ outf) {
  __shared__ u16 As[64 * 32];
  __shared__ u16 Bs[128 * 32];
  const int bm = blockIdx.x, bn = blockIdx.y;
  const int tid = threadIdx.x;
  const int wave = tid >> 6, lane = tid & 63;
  const int wm = (wave & 1) * 32, wn = (wave >> 1) * 64;
  const int row = lane & 15, quad = lane >> 4;
  f32x4 acc[2][4] = {};
  for (int k0 = 0; k0 < DIMC; k0 += 32) {
    {
      int e = tid * 8;
      int rr = e >> 5, col = e & 31;
      gload_lds16(&A[(size_t)(bm * 64 + rr) * DIMC + k0 + col], &As[e]);
    }
    #pragma unroll
    for (int c = 0; c < 2; ++c) {
      int e = c * 2048 + tid * 8;
      int rr = e >> 5, col = e & 31;
      gload_lds16(&Bt[(size_t)(bn * 128 + rr) * DIMC + k0 + col], &Bs[e]);
    }
    __syncthreads();
    bf16x8 a[2], b[4];
    #pragma unroll
    for (int i = 0; i < 2; ++i)
      a[i] = *(const bf16x8*)(&As[(wm + i * 16 + row) * 32 + quad * 8]);
    #pragma unroll
    for (int j = 0; j < 4; ++j)
      b[j] = *(const bf16x8*)(&Bs[(wn + j * 16 + row) * 32 + quad * 8]);
    #pragma unroll
    for (int i = 0; i < 2; ++i)
      #pragma unroll
      for (int j = 0; j < 4; ++j)
        acc[i][j] = __builtin_amdgcn_mfma_f32_16x16x32_bf16(a[i], b[j], acc[i][j], 0, 0, 0);
    __syncthreads();
  }
  #pragma unroll
  for (int i = 0; i < 2; ++i)
    #pragma unroll
    for (int j = 0; j < 4; ++j)
      #pragma unroll
      for (int r = 0; r < 4; ++r) {
        int m = bm * 64 + wm + i * 16 + quad * 4 + r;
        int c = bn * 128 + wn + j * 16 + row;
        outf[(size_t)m * DIMC + c] = acc[i][j][r] + bias[c];
      }
}

// ---------------- fused flash attention (64-q blocks, 64-key double-buffered) ---
// 1024 blocks 1-D; XCD-clustered mapping: bh = (flat&7)*4 + ((flat>>3)&3), so each
// XCD's blocks share only 4 bh -> K/V working set 2MB fits the 4MB per-XCD L2.
// Per 64-key chunk: stage(next) issued BEFORE compute(cur) (T3 minimal 2-phase);
// the end-of-iter __syncthreads (drains vmcnt) finds loads already landed.
// Compute path identical to the proven R0 structure (S^T -> exp -> Ps round-trip
// -> PV with swizzled b128 reads). LDS 37888 B -> 4 blocks/CU.
__global__ __launch_bounds__(256)
void attn_fused(const u16* __restrict__ qh, const u16* __restrict__ kh,
                const u16* __restrict__ vt, u16* __restrict__ ao) {
  __shared__ u16 Ks[2][64 * 64];     // [buf][key][d] chunk-swizzled (8KB each)
  __shared__ u16 Vs[2][64 * 64];     // [buf][d][key] chunk-swizzled (8KB each)
  __shared__ u16 Ps[4][16 * 40];     // per wave [q][32key] stride 40
  const int flat = blockIdx.x;
  const int bh = (flat & 7) * 4 + ((flat >> 3) & 3);
  const int qtile = flat >> 5;
  const int b = bh >> 4, h = bh & 15;
  const int tid = threadIdx.x;
  const int wave = tid >> 6, lane = tid & 63;
  const int qi = lane & 15, quad = lane >> 4;
  const int sw = qi & 7;
  const size_t base = (size_t)bh * NSEQ * HD;
  bf16x8 qf[2];
  {
    int qrow = qtile * 64 + wave * 16 + qi;
    #pragma unroll
    for (int kc = 0; kc < 2; ++kc)
      qf[kc] = *(const bf16x8*)(&qh[base + (size_t)qrow * HD + kc * 32 + quad * 8]);
  }
  // prologue: stage chunk 0 into buffer 0
  #pragma unroll
  for (int c = 0; c < 2; ++c) {
    int p = c * 256 + tid;            // 0..511
    int rk = p >> 3, ck = p & 7;
    gload_lds16(&kh[base + (size_t)rk * HD + (ck ^ (rk & 7)) * 8], &Ks[0][p * 8]);
    gload_lds16(&vt[base + (size_t)rk * NSEQ + (ck ^ (rk & 7)) * 8], &Vs[0][p * 8]);
  }
  __syncthreads();                    // drains vmcnt -> chunk 0 resident
  float li = 0.f;
  f32x4 oacc[4] = {};
  u16* myPs = &Ps[wave][0];
  for (int t = 0; t < NSEQ / 64; ++t) {
    const int cur = t & 1;
    if (t < NSEQ / 64 - 1) {          // issue next chunk's loads BEFORE compute
      #pragma unroll
      for (int c = 0; c < 2; ++c) {
        int p = c * 256 + tid;
        int rk = p >> 3, ck = p & 7;
        gload_lds16(&kh[base + (size_t)((t + 1) * 64 + rk) * HD + (ck ^ (rk & 7)) * 8],
                    &Ks[cur ^ 1][p * 8]);
        gload_lds16(&vt[base + (size_t)rk * NSEQ + (t + 1) * 64 + (ck ^ (rk & 7)) * 8],
                    &Vs[cur ^ 1][p * 8]);
      }
    }
    const u16* Kb = &Ks[cur][0];
    const u16* Vb = &Vs[cur][0];
    #pragma unroll
    for (int kc = 0; kc < 2; ++kc) {
      // S^T[key][q] for 32-key group = two 16-key MFMA tiles
      f32x4 s0 = {}, s1 = {};
      {
        const u16* kr0 = &Kb[((kc * 2) * 16 + qi) * 64];
        const u16* kr1 = &Kb[((kc * 2 + 1) * 16 + qi) * 64];
        __builtin_amdgcn_s_setprio(1);
        s0 = __builtin_amdgcn_mfma_f32_16x16x32_bf16(
            *(const bf16x8*)(&kr0[(quad ^ sw) * 8]), qf[0], s0, 0, 0, 0);
        s0 = __builtin_amdgcn_mfma_f32_16x16x32_bf16(
            *(const bf16x8*)(&kr0[((4 + quad) ^ sw) * 8]), qf[1], s0, 0, 0, 0);
        s1 = __builtin_amdgcn_mfma_f32_16x16x32_bf16(
            *(const bf16x8*)(&kr1[(quad ^ sw) * 8]), qf[0], s1, 0, 0, 0);
        s1 = __builtin_amdgcn_mfma_f32_16x16x32_bf16(
            *(const bf16x8*)(&kr1[((4 + quad) ^ sw) * 8]), qf[1], s1, 0, 0, 0);
        __builtin_amdgcn_s_setprio(0);
      }
      float p0 = EXP2(s0[0]), p1 = EXP2(s0[1]), p2 = EXP2(s0[2]), p3 = EXP2(s0[3]);
      float p4 = EXP2(s1[0]), p5 = EXP2(s1[1]), p6 = EXP2(s1[2]), p7 = EXP2(s1[3]);
      float psum = ((p0 + p1) + (p2 + p3)) + ((p4 + p5) + (p6 + p7));
      {
        u32* w0 = (u32*)(&myPs[qi * 40 + quad * 4]);
        w0[0] = pack_trunc(p0, p1);
        w0[1] = pack_trunc(p2, p3);
        u32* w1 = (u32*)(&myPs[qi * 40 + 16 + quad * 4]);
        w1[0] = pack_trunc(p4, p5);
        w1[1] = pack_trunc(p6, p7);
      }
      psum += __shfl_xor(psum, 16);
      psum += __shfl_xor(psum, 32);
      li += psum;
      asm volatile("" ::: "memory");  // order Ps writes before reads (same wave)
      bf16x8 pf = *(const bf16x8*)(&myPs[qi * 40 + quad * 8]);
      __builtin_amdgcn_s_setprio(1);
      #pragma unroll
      for (int dt = 0; dt < 4; ++dt) {
        bf16x8 vf = *(const bf16x8*)(&Vb[(dt * 16 + qi) * 64 + ((kc * 4 + quad) ^ sw) * 8]);
        oacc[dt] = __builtin_amdgcn_mfma_f32_16x16x32_bf16(vf, pf, oacc[dt], 0, 0, 0);
      }
      __builtin_amdgcn_s_setprio(0);
    }
    __syncthreads();                  // all waves done with buf[cur]; next loads drained
  }
  {
    float inv = 1.0f / li;
    int token = b * NSEQ + qtile * 64 + wave * 16 + qi;
    #pragma unroll
    for (int dt = 0; dt < 4; ++dt) {
      int col = h * 64 + dt * 16 + quad * 4;
      *(u32*)(&ao[(size_t)token * DIMC + col])     = pack_rne(oacc[dt][0] * inv, oacc[dt][1] * inv);
      *(u32*)(&ao[(size_t)token * DIMC + col + 2]) = pack_rne(oacc[dt][2] * inv, oacc[dt][3] * inv);
    }
  }
}

extern "C" void kernel_launch(void* const* d_in, const int* in_sizes, int n_in,
                              void* d_out, int out_size, void* d_ws, size_t ws_size,
                              hipStream_t stream) {
  const float* q    = (const float*)d_in[0];
  const float* k    = (const float*)d_in[1];
  const float* v    = (const float*)d_in[2];
  const float* gq   = (const float*)d_in[3];
  const float* bqln = (const float*)d_in[4];
  const float* gk   = (const float*)d_in[5];
  const float* bkln = (const float*)d_in[6];
  const float* gv   = (const float*)d_in[7];
  const float* bvln = (const float*)d_in[8];
  const float* Wq   = (const float*)d_in[9];
  const float* bq   = (const float*)d_in[10];
  const float* Wk   = (const float*)d_in[11];
  const float* bk   = (const float*)d_in[12];
  const float* Wv   = (const float*)d_in[13];
  const float* bv   = (const float*)d_in[14];
  const float* Wp   = (const float*)d_in[15];
  const float* bp   = (const float*)d_in[16];
  float* out = (float*)d_out;

  char* ws = (char*)d_ws;
  u16* xn  = (u16*)(ws);                          // 3 x 4096x1024 bf16 (24MB)
  u16* wt  = (u16*)(ws + (size_t)25165824);       // 4 x 1024x1024 bf16 (8MB)
  u16* qh  = (u16*)(ws + (size_t)33554432);       // [bh][n][d] bf16 (pre-scaled)
  u16* khb = (u16*)(ws + (size_t)41943040);       // [bh][n][d] bf16
  u16* ao  = (u16*)(ws + (size_t)50331648);       // [token][1024] bf16
  // V^T lives in the output-0 region of d_out (16.78 MB, exactly fits);
  // out_gemm overwrites it afterwards.
  u16* vtb = (u16*)d_out;                         // [bh][d][n] bf16

  const size_t WEL = (size_t)DIMC * DIMC;

  prep<<<3 * MROWS + 4096, 256, 0, stream>>>(q, k, v, gq, bqln, gk, bkln, gv, bvln,
                                             Wq, Wk, Wv, Wp, xn, wt);
  qkv_gemm<<<dim3(MROWS / 128, DIMC / 128, 3), 256, 0, stream>>>(
      xn, wt, bq, bk, bv, out, qh, khb, vtb);
  attn_fused<<<dim3((NSEQ / 64) * BATCH * HEADS), 256, 0, stream>>>(qh, khb, vtb, ao);
  out_gemm<<<dim3(MROWS / 64, DIMC / 128), 256, 0, stream>>>(ao, wt + 3 * WEL, bp, out);
}

// Round 3
// 244.202 us; speedup vs baseline: 1.0981x; 1.0495x over previous
//
#include <hip/hip_runtime.h>
#include <cstdint>

#define DIMC 1024
#define NSEQ 2048
#define BATCH 2
#define HEADS 16
#define HD 64
#define MROWS (BATCH * NSEQ) /* 4096 */

typedef unsigned short u16;
typedef unsigned int u32;
typedef __attribute__((ext_vector_type(8))) short bf16x8;
typedef __attribute__((ext_vector_type(4))) float f32x4;

#if __has_builtin(__builtin_amdgcn_exp2f)
#define EXP2(x) __builtin_amdgcn_exp2f(x)
#else
#define EXP2(x) exp2f(x)
#endif

__device__ __forceinline__ u16 f2bf(float f) {
  union { float f; u32 u; } v; v.f = f;
  u32 u = v.u;
  return (u16)((u + 0x7fffu + ((u >> 16) & 1u)) >> 16);
}
__device__ __forceinline__ u32 pack_rne(float a, float b) {
  return (u32)f2bf(a) | ((u32)f2bf(b) << 16);
}
__device__ __forceinline__ u32 pack_trunc(float a, float b) {
  union { float f; u32 u; } x, y; x.f = a; y.f = b;
  return (x.u >> 16) | (y.u & 0xffff0000u);
}
// async global->LDS, 16B per lane. LDS dest must be wave-uniform base + lane*16.
__device__ __forceinline__ void gload_lds16(const void* g, void* l) {
  __builtin_amdgcn_global_load_lds((const __attribute__((address_space(1))) void*)g,
                                   (__attribute__((address_space(3))) void*)l, 16, 0, 0);
}

// ---------------- prep: LayerNorm+cast (blocks 0..12287) & W transpose+cast ----
__global__ __launch_bounds__(256)
void prep(const float* __restrict__ q, const float* __restrict__ k,
          const float* __restrict__ v,
          const float* __restrict__ gq, const float* __restrict__ bq,
          const float* __restrict__ gk, const float* __restrict__ bk,
          const float* __restrict__ gv, const float* __restrict__ bv,
          const float* __restrict__ w0, const float* __restrict__ w1,
          const float* __restrict__ w2, const float* __restrict__ w3,
          u16* __restrict__ xn, u16* __restrict__ wtout) {
  __shared__ float rs[4], rs2[4];
  __shared__ float tile[32][33];
  int tid = threadIdx.x;
  if (blockIdx.x < 3 * MROWS) {
    int rowid = blockIdx.x;
    int tensor = rowid >> 12;
    int r = rowid & 4095;
    const float *src, *g, *b;
    if (tensor == 0)      { src = q; g = gq; b = bq; }
    else if (tensor == 1) { src = k; g = gk; b = bk; }
    else                  { src = v; g = gv; b = bv; }
    src += (size_t)r * DIMC;
    u16* dst = xn + (size_t)tensor * MROWS * DIMC + (size_t)r * DIMC;
    float4 x = ((const float4*)src)[tid];
    float s  = x.x + x.y + x.z + x.w;
    float s2 = x.x*x.x + x.y*x.y + x.z*x.z + x.w*x.w;
    #pragma unroll
    for (int m = 1; m < 64; m <<= 1) { s += __shfl_xor(s, m); s2 += __shfl_xor(s2, m); }
    int wave = tid >> 6, lane = tid & 63;
    if (lane == 0) { rs[wave] = s; rs2[wave] = s2; }
    __syncthreads();
    s  = rs[0] + rs[1] + rs[2] + rs[3];
    s2 = rs2[0] + rs2[1] + rs2[2] + rs2[3];
    float mu  = s * (1.0f / DIMC);
    float var = s2 * (1.0f / DIMC) - mu * mu;
    float inv = rsqrtf(var + 1e-5f);
    float4 gg = ((const float4*)g)[tid];
    float4 bb = ((const float4*)b)[tid];
    uint2 o;
    o.x = pack_rne((x.x - mu) * inv * gg.x + bb.x, (x.y - mu) * inv * gg.y + bb.y);
    o.y = pack_rne((x.z - mu) * inv * gg.z + bb.z, (x.w - mu) * inv * gg.w + bb.w);
    ((uint2*)dst)[tid] = o;
  } else {
    int blk = blockIdx.x - 3 * MROWS;
    int widx = blk >> 10, t = blk & 1023;
    int ti = t >> 5, tj = t & 31;
    const float* W = (widx == 0) ? w0 : (widx == 1) ? w1 : (widx == 2) ? w2 : w3;
    u16* O = wtout + (size_t)widx * DIMC * DIMC;
    int tx = tid & 31, ty = tid >> 5;
    #pragma unroll
    for (int rr = 0; rr < 32; rr += 8)
      tile[ty + rr][tx] = W[(size_t)(ti * 32 + ty + rr) * DIMC + tj * 32 + tx];
    __syncthreads();
    #pragma unroll
    for (int rr = 0; rr < 32; rr += 8)
      O[(size_t)(tj * 32 + ty + rr) * DIMC + ti * 32 + tx] = f2bf(tile[tx][ty + rr]);
  }
}

// ---------------- fused QKV projection GEMM (grid.z selects Q/K/V) ----------------
// z==2 epilogue also produces V^T [bh][d][n] via LDS transpose (padded stride 136).
__global__ __launch_bounds__(256)
void qkv_gemm(const u16* __restrict__ xn, const u16* __restrict__ wt,
              const float* __restrict__ bq, const float* __restrict__ bk,
              const float* __restrict__ bv,
              float* __restrict__ out, u16* __restrict__ qh,
              u16* __restrict__ khb, u16* __restrict__ vtb) {
  __shared__ u16 smem[128 * 136];           // 34.8 KB; front 16 KB doubles as As/Bs
  u16* As = smem;                            // 128*32
  u16* Bs = smem + 4096;                     // 128*32
  u16* Ls = smem;                            // transpose tile [c][m] stride 136
  const int z = blockIdx.z;
  const u16* A  = xn + (size_t)z * MROWS * DIMC;
  const u16* Bt = wt + (size_t)z * DIMC * DIMC;
  const float* bias = (z == 0) ? bq : (z == 1) ? bk : bv;
  const int bm = blockIdx.x, bn = blockIdx.y;
  const int tid = threadIdx.x;
  const int wave = tid >> 6, lane = tid & 63;
  const int wm = (wave & 1) * 64, wn = (wave >> 1) * 64;
  const int row = lane & 15, quad = lane >> 4;
  const float QSCL = 0.18033688011112042f;  // 0.125 * log2(e)
  f32x4 acc[4][4] = {};
  for (int k0 = 0; k0 < DIMC; k0 += 32) {
    #pragma unroll
    for (int c = 0; c < 2; ++c) {
      int e = c * 2048 + tid * 8;
      int rr = e >> 5, col = e & 31;
      gload_lds16(&A[(size_t)(bm * 128 + rr) * DIMC + k0 + col], &As[e]);
      gload_lds16(&Bt[(size_t)(bn * 128 + rr) * DIMC + k0 + col], &Bs[e]);
    }
    __syncthreads();
    bf16x8 a[4], b[4];
    #pragma unroll
    for (int i = 0; i < 4; ++i)
      a[i] = *(const bf16x8*)(&As[(wm + i * 16 + row) * 32 + quad * 8]);
    #pragma unroll
    for (int j = 0; j < 4; ++j)
      b[j] = *(const bf16x8*)(&Bs[(wn + j * 16 + row) * 32 + quad * 8]);
    #pragma unroll
    for (int i = 0; i < 4; ++i)
      #pragma unroll
      for (int j = 0; j < 4; ++j)
        acc[i][j] = __builtin_amdgcn_mfma_f32_16x16x32_bf16(a[i], b[j], acc[i][j], 0, 0, 0);
    __syncthreads();
  }
  #pragma unroll
  for (int i = 0; i < 4; ++i) {
    #pragma unroll
    for (int j = 0; j < 4; ++j) {
      float val[4];
      #pragma unroll
      for (int r = 0; r < 4; ++r) {
        int m = bm * 128 + wm + i * 16 + quad * 4 + r;
        int c = bn * 128 + wn + j * 16 + row;
        val[r] = acc[i][j][r] + bias[c];
        int b_ = m >> 11, n = m & 2047, h = c >> 6, d = c & 63;
        int bh = b_ * HEADS + h;
        size_t hidx = ((size_t)bh * NSEQ + n) * HD + d;
        if (z == 0) {
          qh[hidx] = f2bf(val[r] * QSCL);   // pre-scaled for attention exp2
        } else {
          out[(size_t)z * MROWS * DIMC + hidx] = val[r];
          if (z == 1) khb[hidx] = f2bf(val[r]);
        }
      }
      if (z == 2) {
        int ct = wn + j * 16 + row;
        int mt = wm + i * 16 + quad * 4;
        u32* L = (u32*)(&Ls[ct * 136 + mt]);
        L[0] = pack_rne(val[0], val[1]);
        L[1] = pack_rne(val[2], val[3]);
      }
    }
  }
  if (z == 2) {
    __syncthreads();
    int b_ = (bm * 128) >> 11;
    int nbase = (bm * 128) & 2047;
    #pragma unroll
    for (int it = 0; it < 8; ++it) {
      int idx = it * 256 + tid;
      int ct = idx >> 4, ch = idx & 15;     // ct = c within tile, ch = 8-m chunk
      uint4 y = *(const uint4*)(&Ls[ct * 136 + ch * 8]);
      int c = bn * 128 + ct;
      int h = c >> 6, d = c & 63;
      size_t o = ((size_t)(b_ * HEADS + h) * HD + d) * NSEQ + nbase + ch * 8;
      *(uint4*)(&vtb[o]) = y;
    }
  }
}

// ---------------- output projection GEMM (64x128 tile, fp32 row-major out) ------
__global__ __launch_bounds__(256)
void out_gemm(const u16* __restrict__ A, const u16* __restrict__ Bt,
              const float* __restrict__ bias, float* __restrict__ outf) {
  __shared__ u16 As[64 * 32];
  __shared__ u16 Bs[128 * 32];
  const int bm = blockIdx.x, bn = blockIdx.y;
  const int tid = threadIdx.x;
  const int wave = tid >> 6, lane = tid & 63;
  const int wm = (wave & 1) * 32, wn = (wave >> 1) * 64;
  const int row = lane & 15, quad = lane >> 4;
  f32x4 acc[2][4] = {};
  for (int k0 = 0; k0 < DIMC; k0 += 32) {
    {
      int e = tid * 8;
      int rr = e >> 5, col = e & 31;
      gload_lds16(&A[(size_t)(bm * 64 + rr) * DIMC + k0 + col], &As[e]);
    }
    #pragma unroll
    for (int c = 0; c < 2; ++c) {
      int e = c * 2048 + tid * 8;
      int rr = e >> 5, col = e & 31;
      gload_lds16(&Bt[(size_t)(bn * 128 + rr) * DIMC + k0 + col], &Bs[e]);
    }
    __syncthreads();
    bf16x8 a[2], b[4];
    #pragma unroll
    for (int i = 0; i < 2; ++i)
      a[i] = *(const bf16x8*)(&As[(wm + i * 16 + row) * 32 + quad * 8]);
    #pragma unroll
    for (int j = 0; j < 4; ++j)
      b[j] = *(const bf16x8*)(&Bs[(wn + j * 16 + row) * 32 + quad * 8]);
    #pragma unroll
    for (int i = 0; i < 2; ++i)
      #pragma unroll
      for (int j = 0; j < 4; ++j)
        acc[i][j] = __builtin_amdgcn_mfma_f32_16x16x32_bf16(a[i], b[j], acc[i][j], 0, 0, 0);
    __syncthreads();
  }
  #pragma unroll
  for (int i = 0; i < 2; ++i)
    #pragma unroll
    for (int j = 0; j < 4; ++j)
      #pragma unroll
      for (int r = 0; r < 4; ++r) {
        int m = bm * 64 + wm + i * 16 + quad * 4 + r;
        int c = bn * 128 + wn + j * 16 + row;
        outf[(size_t)m * DIMC + c] = acc[i][j][r] + bias[c];
      }
}

// ---------------- fused flash attention (128-q blocks, 32 q-rows per wave) ------
// LDS-pipe-bound fix: each wave owns TWO 16-q tiles, so K/V fragment ds_reads are
// issued ONCE and reused for both tiles (DS cycles per q-row ~halved). 512 blocks,
// XCD-clustered bh = (flat&7)*4 + ((flat>>3)&3) (4 bh per XCD -> K/V L2-resident).
// 64-key double-buffered staging, issue-before-compute (R2 pattern, verified).
// psum cross-lane reduction DEFERRED to epilogue (removes 2 ds_bpermute/chunk).
// Ps writes widened to b64. LDS 43 KB -> 3 blocks/CU (grid gives 2).
__global__ __launch_bounds__(256)
void attn_fused(const u16* __restrict__ qh, const u16* __restrict__ kh,
                const u16* __restrict__ vt, u16* __restrict__ ao) {
  __shared__ u16 Ks[2][64 * 64];     // [buf][key][d] chunk-swizzled (8KB each)
  __shared__ u16 Vs[2][64 * 64];     // [buf][d][key] chunk-swizzled (8KB each)
  __shared__ u16 Ps[4][2][16 * 40];  // per wave, per q-subtile [q][32key] stride 40
  const int flat = blockIdx.x;
  const int bh = (flat & 7) * 4 + ((flat >> 3) & 3);
  const int qtile = flat >> 5;       // 0..15, 128 q-rows each
  const int b = bh >> 4, h = bh & 15;
  const int tid = threadIdx.x;
  const int wave = tid >> 6, lane = tid & 63;
  const int qi = lane & 15, quad = lane >> 4;
  const int sw = qi & 7;
  const size_t base = (size_t)bh * NSEQ * HD;
  bf16x8 qf[2][2];                   // [q-subtile][d-half]
  #pragma unroll
  for (int qt = 0; qt < 2; ++qt) {
    int qrow = qtile * 128 + wave * 32 + qt * 16 + qi;
    #pragma unroll
    for (int kc2 = 0; kc2 < 2; ++kc2)
      qf[qt][kc2] = *(const bf16x8*)(&qh[base + (size_t)qrow * HD + kc2 * 32 + quad * 8]);
  }
  // prologue: stage chunk 0 into buffer 0
  #pragma unroll
  for (int c = 0; c < 2; ++c) {
    int p = c * 256 + tid;            // 0..511
    int rk = p >> 3, ck = p & 7;
    gload_lds16(&kh[base + (size_t)rk * HD + (ck ^ (rk & 7)) * 8], &Ks[0][p * 8]);
    gload_lds16(&vt[base + (size_t)rk * NSEQ + (ck ^ (rk & 7)) * 8], &Vs[0][p * 8]);
  }
  __syncthreads();                    // drains vmcnt -> chunk 0 resident
  float li0 = 0.f, li1 = 0.f;
  f32x4 oacc[2][4] = {};
  u16* P0 = &Ps[wave][0][0];
  u16* P1 = &Ps[wave][1][0];
  for (int t = 0; t < NSEQ / 64; ++t) {
    const int cur = t & 1;
    if (t < NSEQ / 64 - 1) {          // issue next chunk's loads BEFORE compute
      #pragma unroll
      for (int c = 0; c < 2; ++c) {
        int p = c * 256 + tid;
        int rk = p >> 3, ck = p & 7;
        gload_lds16(&kh[base + (size_t)((t + 1) * 64 + rk) * HD + (ck ^ (rk & 7)) * 8],
                    &Ks[cur ^ 1][p * 8]);
        gload_lds16(&vt[base + (size_t)rk * NSEQ + (t + 1) * 64 + (ck ^ (rk & 7)) * 8],
                    &Vs[cur ^ 1][p * 8]);
      }
    }
    const u16* Kb = &Ks[cur][0];
    const u16* Vb = &Vs[cur][0];
    #pragma unroll
    for (int kc = 0; kc < 2; ++kc) {
      // K fragments for the two 16-key tiles of this 32-key group (read ONCE,
      // reused for both q-subtiles)
      const u16* kr0 = &Kb[((kc * 2) * 16 + qi) * 64];
      const u16* kr1 = &Kb[((kc * 2 + 1) * 16 + qi) * 64];
      bf16x8 ka0 = *(const bf16x8*)(&kr0[(quad ^ sw) * 8]);
      bf16x8 ka1 = *(const bf16x8*)(&kr0[((4 + quad) ^ sw) * 8]);
      bf16x8 kb0 = *(const bf16x8*)(&kr1[(quad ^ sw) * 8]);
      bf16x8 kb1 = *(const bf16x8*)(&kr1[((4 + quad) ^ sw) * 8]);
      f32x4 s00 = {}, s01 = {}, s10 = {}, s11 = {};   // [q-subtile][key-tile]
      __builtin_amdgcn_s_setprio(1);
      s00 = __builtin_amdgcn_mfma_f32_16x16x32_bf16(ka0, qf[0][0], s00, 0, 0, 0);
      s00 = __builtin_amdgcn_mfma_f32_16x16x32_bf16(ka1, qf[0][1], s00, 0, 0, 0);
      s01 = __builtin_amdgcn_mfma_f32_16x16x32_bf16(kb0, qf[0][0], s01, 0, 0, 0);
      s01 = __builtin_amdgcn_mfma_f32_16x16x32_bf16(kb1, qf[0][1], s01, 0, 0, 0);
      s10 = __builtin_amdgcn_mfma_f32_16x16x32_bf16(ka0, qf[1][0], s10, 0, 0, 0);
      s10 = __builtin_amdgcn_mfma_f32_16x16x32_bf16(ka1, qf[1][1], s10, 0, 0, 0);
      s11 = __builtin_amdgcn_mfma_f32_16x16x32_bf16(kb0, qf[1][0], s11, 0, 0, 0);
      s11 = __builtin_amdgcn_mfma_f32_16x16x32_bf16(kb1, qf[1][1], s11, 0, 0, 0);
      __builtin_amdgcn_s_setprio(0);
      float a0 = EXP2(s00[0]), a1 = EXP2(s00[1]), a2 = EXP2(s00[2]), a3 = EXP2(s00[3]);
      float a4 = EXP2(s01[0]), a5 = EXP2(s01[1]), a6 = EXP2(s01[2]), a7 = EXP2(s01[3]);
      float b0 = EXP2(s10[0]), b1 = EXP2(s10[1]), b2 = EXP2(s10[2]), b3 = EXP2(s10[3]);
      float b4 = EXP2(s11[0]), b5 = EXP2(s11[1]), b6 = EXP2(s11[2]), b7 = EXP2(s11[3]);
      li0 += ((a0 + a1) + (a2 + a3)) + ((a4 + a5) + (a6 + a7));
      li1 += ((b0 + b1) + (b2 + b3)) + ((b4 + b5) + (b6 + b7));
      {
        uint2 w;
        w.x = pack_trunc(a0, a1); w.y = pack_trunc(a2, a3);
        *(uint2*)(&P0[qi * 40 + quad * 4]) = w;
        w.x = pack_trunc(a4, a5); w.y = pack_trunc(a6, a7);
        *(uint2*)(&P0[qi * 40 + 16 + quad * 4]) = w;
        w.x = pack_trunc(b0, b1); w.y = pack_trunc(b2, b3);
        *(uint2*)(&P1[qi * 40 + quad * 4]) = w;
        w.x = pack_trunc(b4, b5); w.y = pack_trunc(b6, b7);
        *(uint2*)(&P1[qi * 40 + 16 + quad * 4]) = w;
      }
      asm volatile("" ::: "memory");  // order Ps writes before reads (same wave)
      bf16x8 pf0 = *(const bf16x8*)(&P0[qi * 40 + quad * 8]);
      bf16x8 pf1 = *(const bf16x8*)(&P1[qi * 40 + quad * 8]);
      __builtin_amdgcn_s_setprio(1);
      #pragma unroll
      for (int dt = 0; dt < 4; ++dt) {
        bf16x8 vf = *(const bf16x8*)(&Vb[(dt * 16 + qi) * 64 + ((kc * 4 + quad) ^ sw) * 8]);
        oacc[0][dt] = __builtin_amdgcn_mfma_f32_16x16x32_bf16(vf, pf0, oacc[0][dt], 0, 0, 0);
        oacc[1][dt] = __builtin_amdgcn_mfma_f32_16x16x32_bf16(vf, pf1, oacc[1][dt], 0, 0, 0);
      }
      __builtin_amdgcn_s_setprio(0);
    }
    __syncthreads();                  // all waves done with buf[cur]; next loads drained
  }
  // deferred cross-lane softmax-denominator reduction (once, not per chunk)
  li0 += __shfl_xor(li0, 16); li0 += __shfl_xor(li0, 32);
  li1 += __shfl_xor(li1, 16); li1 += __shfl_xor(li1, 32);
  #pragma unroll
  for (int qt = 0; qt < 2; ++qt) {
    float inv = 1.0f / (qt == 0 ? li0 : li1);
    int token = b * NSEQ + qtile * 128 + wave * 32 + qt * 16 + qi;
    #pragma unroll
    for (int dt = 0; dt < 4; ++dt) {
      int col = h * 64 + dt * 16 + quad * 4;
      *(u32*)(&ao[(size_t)token * DIMC + col]) =
          pack_rne(oacc[qt][dt][0] * inv, oacc[qt][dt][1] * inv);
      *(u32*)(&ao[(size_t)token * DIMC + col + 2]) =
          pack_rne(oacc[qt][dt][2] * inv, oacc[qt][dt][3] * inv);
    }
  }
}

extern "C" void kernel_launch(void* const* d_in, const int* in_sizes, int n_in,
                              void* d_out, int out_size, void* d_ws, size_t ws_size,
                              hipStream_t stream) {
  const float* q    = (const float*)d_in[0];
  const float* k    = (const float*)d_in[1];
  const float* v    = (const float*)d_in[2];
  const float* gq   = (const float*)d_in[3];
  const float* bqln = (const float*)d_in[4];
  const float* gk   = (const float*)d_in[5];
  const float* bkln = (const float*)d_in[6];
  const float* gv   = (const float*)d_in[7];
  const float* bvln = (const float*)d_in[8];
  const float* Wq   = (const float*)d_in[9];
  const float* bq   = (const float*)d_in[10];
  const float* Wk   = (const float*)d_in[11];
  const float* bk   = (const float*)d_in[12];
  const float* Wv   = (const float*)d_in[13];
  const float* bv   = (const float*)d_in[14];
  const float* Wp   = (const float*)d_in[15];
  const float* bp   = (const float*)d_in[16];
  float* out = (float*)d_out;

  char* ws = (char*)d_ws;
  u16* xn  = (u16*)(ws);                          // 3 x 4096x1024 bf16 (24MB)
  u16* wt  = (u16*)(ws + (size_t)25165824);       // 4 x 1024x1024 bf16 (8MB)
  u16* qh  = (u16*)(ws + (size_t)33554432);       // [bh][n][d] bf16 (pre-scaled)
  u16* khb = (u16*)(ws + (size_t)41943040);       // [bh][n][d] bf16
  u16* ao  = (u16*)(ws + (size_t)50331648);       // [token][1024] bf16
  // V^T lives in the output-0 region of d_out (16.78 MB, exactly fits);
  // out_gemm overwrites it afterwards.
  u16* vtb = (u16*)d_out;                         // [bh][d][n] bf16

  const size_t WEL = (size_t)DIMC * DIMC;

  prep<<<3 * MROWS + 4096, 256, 0, stream>>>(q, k, v, gq, bqln, gk, bkln, gv, bvln,
                                             Wq, Wk, Wv, Wp, xn, wt);
  qkv_gemm<<<dim3(MROWS / 128, DIMC / 128, 3), 256, 0, stream>>>(
      xn, wt, bq, bk, bv, out, qh, khb, vtb);
  attn_fused<<<dim3((NSEQ / 128) * BATCH * HEADS), 256, 0, stream>>>(qh, khb, vtb, ao);
  out_gemm<<<dim3(MROWS / 64, DIMC / 128), 256, 0, stream>>>(ao, wt + 3 * WEL, bp, out);
}